// Round 23
// baseline (425.630 us; speedup 1.0000x reference)
//
#include <hip/hip_runtime.h>
#include <stdint.h>

#define N_NODES 100000
#define N_EDGES 1000000
#define D_IN 128
#define D_OUT 64
#define N_REL 4
#define OUT_STRIDE (N_REL * D_OUT)   // 256
#define STASH_STRIDE 512             // fallback stash stride
#define NH ((size_t)N_NODES * D_IN)

#define M_SCAN (N_REL * N_NODES)     // 400000
#define SCHUNK 2048
#define NSB ((M_SCAN + SCHUNK - 1) / SCHUNK)   // 196
#define REL_CAP 2200000

#define BUCKSZ 512
#define NBUCK ((N_NODES + BUCKSZ - 1) / BUCKSZ)          // 196
#define FILLB 768
#define PERT (FILLB / 256)                               // 3
#define ECHUNK ((N_EDGES + FILLB - 1) / FILLB)           // 1302
#define P2CAP 12288

#define GEMMG ((N_NODES + 63) / 64)  // 1563
#define GATHG ((N_NODES + 15) / 16)  // 6250
#define NXB   ((N_NODES * (D_IN / 4) + 255) / 256)   // 12500

typedef short s16x8 __attribute__((ext_vector_type(8)));
typedef float f32x4 __attribute__((ext_vector_type(4)));

__device__ inline float b2f(unsigned short u) {
    union { unsigned int i; float f; } v;
    v.i = ((unsigned int)u) << 16;
    return v.f;
}
__device__ inline unsigned short f2b(float f) {
    union { float f; unsigned int i; } v;
    v.f = f;
    unsigned int r = v.i + 0x7FFF + ((v.i >> 16) & 1);   // rne
    return (unsigned short)(r >> 16);
}

__device__ inline bool read_mask(const uint8_t* mask8, int bytemode, size_t idx) {
    return bytemode ? (mask8[idx] != 0) : (((const int*)mask8)[idx] != 0);
}

__device__ inline int scan_val(const unsigned long long* degu, int i) {
    int r = i / N_NODES;
    int n = i - r * N_NODES;
    return (int)((degu[n] >> (16 * r)) & 0xFFFF);
}

// ---- fused preprocessing head: binA | detect | pack_w | xb ----
__device__ inline void binA_body(const int* __restrict__ dst, int* __restrict__ gcount,
                                 int blk) {
    __shared__ int h[NBUCK];
    for (int i = threadIdx.x; i < NBUCK; i += 256) h[i] = 0;
    __syncthreads();
    int e0 = blk * ECHUNK;
    int e1 = min(e0 + ECHUNK, N_EDGES);
    for (int e = e0 + threadIdx.x; e < e1; e += 256)
        atomicAdd(&h[dst[e] >> 9], 1);
    __syncthreads();
    for (int i = threadIdx.x; i < NBUCK; i += 256)
        gcount[blk * NBUCK + i] = h[i];
}

__device__ inline void detect_body(const uint8_t* __restrict__ mask, int* __restrict__ flag,
                                   int blk) {
    unsigned int u = ((const unsigned int*)mask)[blk * 256 + threadIdx.x];
    bool hit = (u & 0xFFFFFF00u) != 0;
    if (__any(hit) && (threadIdx.x & 63) == 0)
        atomicOr(flag, 1);
}

__device__ inline void packw_body(const float* __restrict__ W, unsigned short* __restrict__ Wpk,
                                  int blk) {
    int t = blk * 256 + threadIdx.x;
    if (t >= N_REL * 12 * 4 * 64) return;
    int lane = t & 63;
    int nb   = (t >> 6) & 3;
    int ks   = (t >> 8) % 12;
    int r    = t / 3072;
    const float* Wr = W + (size_t)r * 384 * 64;
    int k0 = ks * 32 + (lane >> 4) * 8;
    int n  = nb * 16 + (lane & 15);
    unsigned short* o = Wpk + (size_t)t * 8;
#pragma unroll
    for (int i = 0; i < 8; ++i)
        o[i] = f2b(Wr[(size_t)(k0 + i) * 64 + n]);
}

__device__ inline void xb_body(const float* __restrict__ x, unsigned short* __restrict__ xb,
                               int blk) {
    int i = blk * 256 + threadIdx.x;
    if (i >= N_NODES * (D_IN / 4)) return;
    float4 v = ((const float4*)x)[i];
    ushort4 u;
    u.x = f2b(v.x); u.y = f2b(v.y); u.z = f2b(v.z); u.w = f2b(v.w);
    ((ushort4*)xb)[i] = u;
}

__global__ __launch_bounds__(256) void front_kernel(const int* __restrict__ dst,
                                                    const uint8_t* __restrict__ mask,
                                                    const float* __restrict__ W,
                                                    const float* __restrict__ x,
                                                    int* __restrict__ gcount,
                                                    int* __restrict__ flag,
                                                    unsigned short* __restrict__ Wpk,
                                                    unsigned short* __restrict__ xb,
                                                    int do_xb) {
    int k = blockIdx.x;
    if (k < FILLB) { binA_body(dst, gcount, k); return; }
    k -= FILLB;
    if (k < 64) { detect_body(mask, flag, k); return; }
    k -= 64;
    if (k < 48) { packw_body(W, Wpk, k); return; }
    k -= 48;
    if (do_xb) xb_body(x, xb, k);
}

// ---- scans ----
__global__ __launch_bounds__(256) void scan_reduce_kernel(const unsigned long long* __restrict__ degu,
                                                          int* __restrict__ bsum) {
    __shared__ int sm[256];
    int b = blockIdx.x, t = threadIdx.x;
    int base = b * SCHUNK + t * 8;
    int s = 0;
#pragma unroll
    for (int i = 0; i < 8; ++i) {
        int idx = base + i;
        if (idx < M_SCAN) s += scan_val(degu, idx);
    }
    sm[t] = s;
    __syncthreads();
    for (int st = 128; st > 0; st >>= 1) {
        if (t < st) sm[t] += sm[t + st];
        __syncthreads();
    }
    if (t == 0) bsum[b] = sm[0];
}

__global__ __launch_bounds__(256) void scan_mid_kernel(const int* __restrict__ bsum,
                                                       int* __restrict__ boff,
                                                       int* __restrict__ rel_rp) {
    __shared__ int sm[256];
    int t = threadIdx.x;
    int v = (t < NSB) ? bsum[t] : 0;
    sm[t] = v;
    __syncthreads();
    for (int st = 1; st < 256; st <<= 1) {
        int u = (t >= st) ? sm[t - st] : 0;
        __syncthreads();
        sm[t] += u;
        __syncthreads();
    }
    if (t < NSB) boff[t] = sm[t] - v;
    if (t == NSB - 1) rel_rp[M_SCAN] = sm[t];
}

__global__ __launch_bounds__(256) void scan_final_kernel(const unsigned long long* __restrict__ degu,
                                                         const int* __restrict__ boff,
                                                         int* __restrict__ rel_rp) {
    __shared__ int sm[256];
    int b = blockIdx.x, t = threadIdx.x;
    int base = b * SCHUNK + t * 8;
    int v[8];
    int s = 0;
#pragma unroll
    for (int i = 0; i < 8; ++i) {
        int idx = base + i;
        v[i] = (idx < M_SCAN) ? scan_val(degu, idx) : 0;
        s += v[i];
    }
    sm[t] = s;
    __syncthreads();
    for (int st = 1; st < 256; st <<= 1) {
        int u = (t >= st) ? sm[t - st] : 0;
        __syncthreads();
        sm[t] += u;
        __syncthreads();
    }
    int run = sm[t] - s + boff[b];
#pragma unroll
    for (int i = 0; i < 8; ++i) {
        int idx = base + i;
        if (idx < M_SCAN) { rel_rp[idx] = run; run += v[i]; }
    }
}

// ---- radix CSR build ----
__global__ __launch_bounds__(256) void mscan_col_kernel(const int* __restrict__ gcount,
                                                        int* __restrict__ gbase,
                                                        int* __restrict__ btot) {
    __shared__ int sm[256];
    const int bk = blockIdx.x;
    const int t  = threadIdx.x;
    int v[PERT];
    int s = 0;
#pragma unroll
    for (int i = 0; i < PERT; ++i) {
        int blk = t * PERT + i;
        v[i] = gcount[blk * NBUCK + bk];
        s += v[i];
    }
    sm[t] = s;
    __syncthreads();
    for (int st = 1; st < 256; st <<= 1) {
        int u = (t >= st) ? sm[t - st] : 0;
        __syncthreads();
        sm[t] += u;
        __syncthreads();
    }
    int run = sm[t] - s;
#pragma unroll
    for (int i = 0; i < PERT; ++i) {
        int blk = t * PERT + i;
        gbase[blk * NBUCK + bk] = run;
        run += v[i];
    }
    if (t == 255) btot[bk] = run;
}

__global__ __launch_bounds__(256) void mscan_row_kernel(const int* __restrict__ btot,
                                                        int* __restrict__ bucketbase) {
    __shared__ int sm[256];
    int t = threadIdx.x;
    int v = (t < NBUCK) ? btot[t] : 0;
    sm[t] = v;
    __syncthreads();
    for (int st = 1; st < 256; st <<= 1) {
        int u = (t >= st) ? sm[t - st] : 0;
        __syncthreads();
        sm[t] += u;
        __syncthreads();
    }
    if (t < NBUCK) bucketbase[t] = sm[t] - v;
    if (t == NBUCK - 1) bucketbase[NBUCK] = sm[t];
}

// rec = src(17b) | dstlocal(9b)<<17 | maskbits(4b)<<26
__global__ __launch_bounds__(256) void binB_kernel(const int* __restrict__ src,
                                                   const int* __restrict__ dst,
                                                   const uint8_t* __restrict__ mask,
                                                   const int* __restrict__ flag,
                                                   const int* __restrict__ gbase,
                                                   const int* __restrict__ bucketbase,
                                                   unsigned int* __restrict__ recs) {
    __shared__ int cur[NBUCK];
    for (int i = threadIdx.x; i < NBUCK; i += 256) cur[i] = 0;
    __syncthreads();
    int bm = *flag;
    int e0 = blockIdx.x * ECHUNK;
    int e1 = min(e0 + ECHUNK, N_EDGES);
    for (int e = e0 + threadIdx.x; e < e1; e += 256) {
        int d = dst[e], s = src[e];
        int bits = 0;
        if (read_mask(mask, bm, (size_t)0 * N_EDGES + e)) bits |= 1;
        if (read_mask(mask, bm, (size_t)1 * N_EDGES + e)) bits |= 2;
        if (read_mask(mask, bm, (size_t)2 * N_EDGES + e)) bits |= 4;
        if (read_mask(mask, bm, (size_t)3 * N_EDGES + e)) bits |= 8;
        int bk  = d >> 9;
        int loc = atomicAdd(&cur[bk], 1);
        int pos = bucketbase[bk] + gbase[blockIdx.x * NBUCK + bk] + loc;
        recs[pos] = (unsigned)s | ((unsigned)(d & 511) << 17) | ((unsigned)bits << 26);
    }
}

// masked degrees from recs -> degu packed + norm
__global__ __launch_bounds__(256) void count_norm_kernel(const unsigned int* __restrict__ recs,
                                                         const int* __restrict__ bucketbase,
                                                         unsigned long long* __restrict__ degu,
                                                         float* __restrict__ norm) {
    __shared__ int cnt[4 * BUCKSZ];
    const int t = threadIdx.x, b = blockIdx.x;
    const int lo = b * BUCKSZ;
    const int hi = min(lo + BUCKSZ, N_NODES);
    for (int i = t; i < 4 * BUCKSZ; i += 256) cnt[i] = 0;
    __syncthreads();

    const int e0 = bucketbase[b], e1 = bucketbase[b + 1];
    for (int i = e0 + t; i < e1; i += 256) {
        unsigned rec = recs[i];
        int dl   = (rec >> 17) & 0x1FF;
        int bits = (rec >> 26) & 0xF;
#pragma unroll
        for (int r = 0; r < 4; ++r)
            if ((bits >> r) & 1) atomicAdd(&cnt[r * BUCKSZ + dl], 1);
    }
    __syncthreads();

    for (int n = lo + t; n < hi; n += 256) {
        int dl = n - lo;
        unsigned long long u = 0;
#pragma unroll
        for (int r = 0; r < 4; ++r) {
            int c = cnt[r * BUCKSZ + dl];
            u |= ((unsigned long long)(c & 0xFFFF)) << (16 * r);
            norm[r * N_NODES + n] = 1.0f / sqrtf(fmaxf((float)c, 1.0f));
        }
        degu[n] = u;
    }
}

// one block per bucket: build per-(r,node) CSR in LDS, stream out.
__global__ __launch_bounds__(256) void csr_kernel(const unsigned int* __restrict__ recs,
                                                  const int* __restrict__ bucketbase,
                                                  const int* __restrict__ rel_rp,
                                                  int* __restrict__ rel_src) {
    __shared__ int cur[4 * BUCKSZ];
    __shared__ int lb[5];
    __shared__ int csr[P2CAP];
    const int t = threadIdx.x, b = blockIdx.x;
    const int lo = b * BUCKSZ;
    const int hi = min(lo + BUCKSZ, N_NODES);

    if (t == 0) {
        int run = 0;
#pragma unroll
        for (int r = 0; r < 4; ++r) {
            lb[r] = run;
            run += rel_rp[r * N_NODES + hi] - rel_rp[r * N_NODES + lo];
        }
        lb[4] = run;
    }
    __syncthreads();
    const int tot  = lb[4];
    const bool fits = (tot <= P2CAP);

#pragma unroll
    for (int r = 0; r < 4; ++r)
        for (int n = lo + t; n < hi; n += 256)
            cur[r * BUCKSZ + (n - lo)] = rel_rp[r * N_NODES + n] - rel_rp[r * N_NODES + lo];
    __syncthreads();

    const int e0 = bucketbase[b], e1 = bucketbase[b + 1];
    for (int i = e0 + t; i < e1; i += 256) {
        unsigned rec = recs[i];
        int s    = rec & 0x1FFFF;
        int dl   = (rec >> 17) & 0x1FF;
        int bits = (rec >> 26) & 0xF;
#pragma unroll
        for (int r = 0; r < 4; ++r) {
            if ((bits >> r) & 1) {
                int k = atomicAdd(&cur[r * BUCKSZ + dl], 1);
                if (fits) csr[lb[r] + k] = s;
                else      rel_src[rel_rp[r * N_NODES + lo] + k] = s;
            }
        }
    }
    __syncthreads();

    if (fits) {
        for (int j = t; j < tot; j += 256) {
            int r = (j >= lb[1]) + (j >= lb[2]) + (j >= lb[3]);
            rel_src[rel_rp[r * N_NODES + lo] + (j - lb[r])] = csr[j];
        }
    }
}

// ---- gather body (strides in elements) ----
template <int BF16IN>
__device__ inline void gather_body(const void* __restrict__ hin_, int in_stride,
                                   const int* __restrict__ rp,
                                   const int* __restrict__ rel_src,
                                   const float* __restrict__ normr,
                                   unsigned short* __restrict__ hout, int out_stride,
                                   int blk) {
    const int lane = threadIdx.x & 63;
    const int wave = (blk * 256 + (int)threadIdx.x) >> 6;
    const int g    = lane >> 4;
    const int l16  = lane & 15;
    const int node = wave * 4 + g;
    const int fb   = l16 * 8;

    const bool valid = (node < N_NODES);
    int e0 = valid ? rp[node] : 0;
    int e1 = valid ? rp[node + 1] : 0;

    float a[8];
#pragma unroll
    for (int j = 0; j < 8; ++j) a[j] = 0.0f;

    for (int base = e0; base < e1; base += 16) {
        int m = min(16, e1 - base);
        int   s_l = (l16 < m) ? rel_src[base + l16] : 0;
        float w_l = (l16 < m) ? normr[s_l] : 0.0f;

        for (int i = 0; i < m; i += 4) {
            int   i1 = min(i + 1, m - 1), i2 = min(i + 2, m - 1), i3 = min(i + 3, m - 1);
            int   s0 = __shfl(s_l, i,  16);
            int   s1 = __shfl(s_l, i1, 16);
            int   s2 = __shfl(s_l, i2, 16);
            int   s3 = __shfl(s_l, i3, 16);
            float w0 = __shfl(w_l, i,  16);
            float w1 = (i + 1 < m) ? __shfl(w_l, i1, 16) : 0.0f;
            float w2 = (i + 2 < m) ? __shfl(w_l, i2, 16) : 0.0f;
            float w3 = (i + 3 < m) ? __shfl(w_l, i3, 16) : 0.0f;

            if (BF16IN) {
                const unsigned short* hp = (const unsigned short*)hin_;
                s16x8 v0 = *(const s16x8*)(hp + (size_t)s0 * in_stride + fb);
                s16x8 v1 = *(const s16x8*)(hp + (size_t)s1 * in_stride + fb);
                s16x8 v2 = *(const s16x8*)(hp + (size_t)s2 * in_stride + fb);
                s16x8 v3 = *(const s16x8*)(hp + (size_t)s3 * in_stride + fb);
#pragma unroll
                for (int j = 0; j < 8; ++j) {
                    a[j] += w0 * b2f((unsigned short)v0[j]);
                    a[j] += w1 * b2f((unsigned short)v1[j]);
                    a[j] += w2 * b2f((unsigned short)v2[j]);
                    a[j] += w3 * b2f((unsigned short)v3[j]);
                }
            } else {
                const float* xp = (const float*)hin_;
                float4 u0  = *(const float4*)(xp + (size_t)s0 * in_stride + fb);
                float4 u0b = *(const float4*)(xp + (size_t)s0 * in_stride + fb + 4);
                float4 u1  = *(const float4*)(xp + (size_t)s1 * in_stride + fb);
                float4 u1b = *(const float4*)(xp + (size_t)s1 * in_stride + fb + 4);
                float4 u2  = *(const float4*)(xp + (size_t)s2 * in_stride + fb);
                float4 u2b = *(const float4*)(xp + (size_t)s2 * in_stride + fb + 4);
                float4 u3  = *(const float4*)(xp + (size_t)s3 * in_stride + fb);
                float4 u3b = *(const float4*)(xp + (size_t)s3 * in_stride + fb + 4);
                a[0] += w0 * u0.x + w1 * u1.x + w2 * u2.x + w3 * u3.x;
                a[1] += w0 * u0.y + w1 * u1.y + w2 * u2.y + w3 * u3.y;
                a[2] += w0 * u0.z + w1 * u1.z + w2 * u2.z + w3 * u3.z;
                a[3] += w0 * u0.w + w1 * u1.w + w2 * u2.w + w3 * u3.w;
                a[4] += w0 * u0b.x + w1 * u1b.x + w2 * u2b.x + w3 * u3b.x;
                a[5] += w0 * u0b.y + w1 * u1b.y + w2 * u2b.y + w3 * u3b.y;
                a[6] += w0 * u0b.z + w1 * u1b.z + w2 * u2b.z + w3 * u3b.z;
                a[7] += w0 * u0b.w + w1 * u1b.w + w2 * u2b.w + w3 * u3b.w;
            }
        }
    }

    if (valid) {
        float c = normr[node];
        s16x8 r;
#pragma unroll
        for (int j = 0; j < 8; ++j) r[j] = (short)f2b(a[j] * c);
        *(s16x8*)(hout + (size_t)node * out_stride + fb) = r;
    }
}

template <int BF16IN>
__global__ __launch_bounds__(256) void gather_kernel(const void* __restrict__ hin_, int in_stride,
                                                     const int* __restrict__ rp,
                                                     const int* __restrict__ rel_src,
                                                     const float* __restrict__ normr,
                                                     unsigned short* __restrict__ hout, int out_stride) {
    gather_body<BF16IN>(hin_, in_stride, rp, rel_src, normr, hout, out_stride, blockIdx.x);
}

// ---- gemm body (h1 stride parametrized: D_IN dense or STASH_STRIDE fallback) ----
template <int XB16>
__device__ inline void gemm_body(const void* __restrict__ x_,
                                 const unsigned short* __restrict__ h1s, int h1_stride,
                                 const unsigned short* __restrict__ h2b,
                                 const unsigned short* __restrict__ Wpk,
                                 const float* __restrict__ bias,
                                 float* __restrict__ out,
                                 int blk) {
    const int wave = threadIdx.x >> 6;
    const int lane = threadIdx.x & 63;
    const int rb   = blk * 64 + wave * 16;
    const int row  = min(rb + (lane & 15), N_NODES - 1);
    const int kq   = (lane >> 4) * 8;

    f32x4 acc0 = {0.f, 0.f, 0.f, 0.f};
    f32x4 acc1 = {0.f, 0.f, 0.f, 0.f};
    f32x4 acc2 = {0.f, 0.f, 0.f, 0.f};
    f32x4 acc3 = {0.f, 0.f, 0.f, 0.f};

    const s16x8* Wf = (const s16x8*)Wpk;

#pragma unroll
    for (int ks = 0; ks < 12; ++ks) {
        s16x8 a;
        const int koff = (ks & 3) * 32 + kq;
        if (ks < 4) {
            if (XB16) {
                a = *(const s16x8*)((const unsigned short*)x_ + (size_t)row * D_IN + koff);
            } else {
                const float* p = (const float*)x_ + (size_t)row * D_IN + koff;
                float4 f0 = *(const float4*)p;
                float4 f1 = *(const float4*)(p + 4);
                a[0] = (short)f2b(f0.x); a[1] = (short)f2b(f0.y);
                a[2] = (short)f2b(f0.z); a[3] = (short)f2b(f0.w);
                a[4] = (short)f2b(f1.x); a[5] = (short)f2b(f1.y);
                a[6] = (short)f2b(f1.z); a[7] = (short)f2b(f1.w);
            }
        } else if (ks < 8) {
            a = *(const s16x8*)(h1s + (size_t)row * h1_stride + koff);
        } else {
            a = *(const s16x8*)(h2b + (size_t)row * D_IN + koff);
        }
        const s16x8* bks = Wf + ks * 256 + lane;
        acc0 = __builtin_amdgcn_mfma_f32_16x16x32_bf16(a, bks[0],   acc0, 0, 0, 0);
        acc1 = __builtin_amdgcn_mfma_f32_16x16x32_bf16(a, bks[64],  acc1, 0, 0, 0);
        acc2 = __builtin_amdgcn_mfma_f32_16x16x32_bf16(a, bks[128], acc2, 0, 0, 0);
        acc3 = __builtin_amdgcn_mfma_f32_16x16x32_bf16(a, bks[192], acc3, 0, 0, 0);
    }

    __syncthreads();   // protects fallback (h1s aliases out); negligible otherwise

    const int orow0 = rb + (lane >> 4) * 4;
    const int jc    = lane & 15;
    f32x4 accs[4] = {acc0, acc1, acc2, acc3};
#pragma unroll
    for (int nb = 0; nb < 4; ++nb) {
        float bz = bias[nb * 16 + jc];
#pragma unroll
        for (int i = 0; i < 4; ++i) {
            int n = orow0 + i;
            if (n < N_NODES)
                out[(size_t)n * OUT_STRIDE + nb * 16 + jc] = fmaxf(accs[nb][i] + bz, 0.0f);
        }
    }
}

template <int XB16>
__global__ __launch_bounds__(256) void gemm_kernel(const void* __restrict__ x_,
                                                   const unsigned short* __restrict__ h1s, int h1_stride,
                                                   const unsigned short* __restrict__ h2b,
                                                   const unsigned short* __restrict__ Wpk,
                                                   const float* __restrict__ bias,
                                                   float* __restrict__ out) {
    gemm_body<XB16>(x_, h1s, h1_stride, h2b, Wpk, bias, out, blockIdx.x);
}

// fused: gemm(r)[h1cur] + hop1(r+1)->h1next; contiguous role split
template <int XB16>
__global__ __launch_bounds__(256) void fused_kernel(const void* __restrict__ x_,
                                                    const unsigned short* __restrict__ h1cur, int h1c_stride,
                                                    const unsigned short* __restrict__ h2b,
                                                    const unsigned short* __restrict__ Wpk,
                                                    const float* __restrict__ bias,
                                                    float* __restrict__ out,
                                                    const int* __restrict__ rp_n,
                                                    const int* __restrict__ rel_src,
                                                    const float* __restrict__ norm_n,
                                                    unsigned short* __restrict__ h1next, int h1n_stride) {
    if (blockIdx.x < GEMMG) {
        gemm_body<XB16>(x_, h1cur, h1c_stride, h2b, Wpk, bias, out, blockIdx.x);
    } else {
        gather_body<XB16>(x_, D_IN, rp_n, rel_src, norm_n, h1next, h1n_stride,
                          blockIdx.x - GEMMG);
    }
}

extern "C" void kernel_launch(void* const* d_in, const int* in_sizes, int n_in,
                              void* d_out, int out_size, void* d_ws, size_t ws_size,
                              hipStream_t stream) {
    const float*   x    = (const float*)d_in[0];
    const int*     src  = (const int*)d_in[1];
    const int*     dst  = (const int*)d_in[2];
    const uint8_t* mask = (const uint8_t*)d_in[3];
    const float*   W    = (const float*)d_in[4];     // [4][384][64]
    const float*   b    = (const float*)d_in[5];     // [4][64]
    float*         out  = (float*)d_out;             // [N][256]

    int*                flag    = (int*)d_ws;
    unsigned long long* degu    = (unsigned long long*)((char*)d_ws + 256);
    float*              norm    = (float*)(degu + N_NODES);
    int*                rel_rp  = (int*)(norm + (size_t)N_REL * N_NODES);
    int*                bsum    = rel_rp + M_SCAN + 16;
    int*                boff    = bsum + 256;
    int*                gcount  = boff + 256;
    int*                gbase   = gcount + FILLB * NBUCK;
    int*                bktbase = gbase + FILLB * NBUCK;
    int*                btot    = bktbase + 256;
    unsigned int*       recs    = (unsigned int*)(btot + 256);
    int*                rel_src = (int*)(recs + N_EDGES);
    unsigned short*     Wpk     = (unsigned short*)(rel_src + REL_CAP);
    unsigned short*     h2_0    = Wpk + 12288 * 8;
    // dense path: h1[2], xb follow; shallow: xb aliases h1_0
    unsigned short*     h1_0    = h2_0 + NH;
    unsigned short*     h1_1    = h1_0 + NH;
    unsigned short*     xb_den  = h1_1 + NH;
    unsigned short*     xb_shal = h2_0 + NH;

    const size_t need_den  = (size_t)((char*)(xb_den + NH) - (char*)d_ws);
    const size_t need_shal = (size_t)((char*)(xb_shal + NH) - (char*)d_ws);
    const int dense  = (ws_size >= need_den);
    const int use_xb = dense || (ws_size >= need_shal);
    unsigned short* xb = dense ? xb_den : xb_shal;

    hipMemsetAsync(d_ws, 0, 256, stream);

    front_kernel<<<FILLB + 64 + 48 + (use_xb ? NXB : 0), 256, 0, stream>>>(
        dst, mask, W, x, gcount, flag, Wpk, xb, use_xb);

    mscan_col_kernel<<<NBUCK, 256, 0, stream>>>(gcount, gbase, btot);
    mscan_row_kernel<<<1, 256, 0, stream>>>(btot, bktbase);
    binB_kernel<<<FILLB, 256, 0, stream>>>(src, dst, mask, flag, gbase, bktbase, recs);

    count_norm_kernel<<<NBUCK, 256, 0, stream>>>(recs, bktbase, degu, norm);

    scan_reduce_kernel<<<NSB, 256, 0, stream>>>(degu, bsum);
    scan_mid_kernel<<<1, 256, 0, stream>>>(bsum, boff, rel_rp);
    scan_final_kernel<<<NSB, 256, 0, stream>>>(degu, boff, rel_rp);

    csr_kernel<<<NBUCK, 256, 0, stream>>>(recs, bktbase, rel_rp, rel_src);

    const void* xin = use_xb ? (const void*)xb : (const void*)x;

    if (dense) {
        // r19 schedule with dense h1[2]: gemm(r) reads h1[r&1];
        // hop1(r+1) writes h1[(r+1)&1]; serial hop2(r+1) reads h1[(r+1)&1].
        unsigned short* h1buf[2] = {h1_0, h1_1};

        gather_kernel<1><<<GATHG, 256, 0, stream>>>(xin, D_IN, rel_rp, rel_src,
                                                    norm, h1buf[0], D_IN);
        gather_kernel<1><<<GATHG, 256, 0, stream>>>(h1buf[0], D_IN, rel_rp, rel_src,
                                                    norm, h2_0, D_IN);

        for (int r = 0; r < N_REL; ++r) {
            const unsigned short* Wr = Wpk + (size_t)r * 3072 * 8;
            const float* br = b + (size_t)r * D_OUT;
            float* outr = out + (size_t)r * D_OUT;
            if (r < N_REL - 1) {
                const int*   rp1 = rel_rp + (size_t)(r + 1) * N_NODES;
                const float* n1  = norm + (size_t)(r + 1) * N_NODES;
                fused_kernel<1><<<GEMMG + GATHG, 256, 0, stream>>>(
                    xin, h1buf[r & 1], D_IN, h2_0, Wr, br, outr,
                    rp1, rel_src, n1, h1buf[(r + 1) & 1], D_IN);
                gather_kernel<1><<<GATHG, 256, 0, stream>>>(h1buf[(r + 1) & 1], D_IN,
                                                            rp1, rel_src, n1, h2_0, D_IN);
            } else {
                gemm_kernel<1><<<GEMMG, 256, 0, stream>>>(xin, h1buf[r & 1], D_IN,
                                                          h2_0, Wr, br, outr);
            }
        }
    } else {
        // shallow fallback: h1 stash in out
        unsigned short* stash[N_REL];
        for (int r = 0; r < N_REL; ++r)
            stash[r] = (unsigned short*)out + (size_t)r * 128;

        if (use_xb)
            gather_kernel<1><<<GATHG, 256, 0, stream>>>(xin, D_IN, rel_rp, rel_src,
                                                        norm, stash[0], STASH_STRIDE);
        else
            gather_kernel<0><<<GATHG, 256, 0, stream>>>(xin, D_IN, rel_rp, rel_src,
                                                        norm, stash[0], STASH_STRIDE);
        gather_kernel<1><<<GATHG, 256, 0, stream>>>(stash[0], STASH_STRIDE, rel_rp, rel_src,
                                                    norm, h2_0, D_IN);

        for (int r = 0; r < N_REL; ++r) {
            const unsigned short* Wr = Wpk + (size_t)r * 3072 * 8;
            const float* br = b + (size_t)r * D_OUT;
            float* outr = out + (size_t)r * D_OUT;
            if (r < N_REL - 1) {
                const float* n1  = norm + (size_t)(r + 1) * N_NODES;
                const int*   rp1 = rel_rp + (size_t)(r + 1) * N_NODES;
                if (use_xb)
                    fused_kernel<1><<<GEMMG + GATHG, 256, 0, stream>>>(
                        xin, stash[r], STASH_STRIDE, h2_0, Wr, br, outr,
                        rp1, rel_src, n1, stash[r + 1], STASH_STRIDE);
                else
                    fused_kernel<0><<<GEMMG + GATHG, 256, 0, stream>>>(
                        xin, stash[r], STASH_STRIDE, h2_0, Wr, br, outr,
                        rp1, rel_src, n1, stash[r + 1], STASH_STRIDE);
                gather_kernel<1><<<GATHG, 256, 0, stream>>>(stash[r + 1], STASH_STRIDE,
                                                            rp1, rel_src, n1, h2_0, D_IN);
            } else {
                if (use_xb)
                    gemm_kernel<1><<<GEMMG, 256, 0, stream>>>(xin, stash[r], STASH_STRIDE,
                                                              h2_0, Wr, br, outr);
                else
                    gemm_kernel<0><<<GEMMG, 256, 0, stream>>>(xin, stash[r], STASH_STRIDE,
                                                              h2_0, Wr, br, outr);
            }
        }
    }
}

// Round 24
// 388.589 us; speedup vs baseline: 1.0953x; 1.0953x over previous
//
#include <hip/hip_runtime.h>
#include <stdint.h>

#define N_NODES 100000
#define N_EDGES 1000000
#define D_IN 128
#define D_OUT 64
#define N_REL 4
#define OUT_STRIDE (N_REL * D_OUT)   // 256
#define STASH_STRIDE 512             // ushorts per out row (256 floats)
#define NH ((size_t)N_NODES * D_IN)  // elements per h buffer

#define M_SCAN (N_REL * N_NODES)     // 400000
#define SCHUNK 2048
#define NSB ((M_SCAN + SCHUNK - 1) / SCHUNK)   // 196 (<=256)
#define REL_CAP 2200000

#define BUCKSZ 512
#define NBUCK ((N_NODES + BUCKSZ - 1) / BUCKSZ)          // 196
#define FILLB 768
#define PERT (FILLB / 256)                               // 3
#define ECHUNK ((N_EDGES + FILLB - 1) / FILLB)           // 1302
#define P2CAP 12288

#define GEMMG ((N_NODES + 63) / 64)  // 1563
#define GATHG ((N_NODES + 15) / 16)  // 6250

typedef short s16x8 __attribute__((ext_vector_type(8)));
typedef float f32x4 __attribute__((ext_vector_type(4)));

__device__ inline float b2f(unsigned short u) {
    union { unsigned int i; float f; } v;
    v.i = ((unsigned int)u) << 16;
    return v.f;
}
__device__ inline unsigned short f2b(float f) {
    union { float f; unsigned int i; } v;
    v.f = f;
    unsigned int r = v.i + 0x7FFF + ((v.i >> 16) & 1);   // rne
    return (unsigned short)(r >> 16);
}

// flag=1 if mask is 1-byte bools, 0 if int32.
__global__ __launch_bounds__(256) void detect_mask_kernel(const uint8_t* __restrict__ mask,
                                                          int* __restrict__ flag) {
    unsigned int u = ((const unsigned int*)mask)[blockIdx.x * 256 + threadIdx.x];
    bool hit = (u & 0xFFFFFF00u) != 0;
    if (__ballot(hit)) {
        if ((threadIdx.x & 63) == 0 && __any(hit))
            atomicOr(flag, 1);
    }
}

__device__ inline bool read_mask(const uint8_t* mask8, int bytemode, size_t idx) {
    return bytemode ? (mask8[idx] != 0) : (((const int*)mask8)[idx] != 0);
}

__device__ inline int scan_val(const unsigned long long* degu, int i) {
    int r = i / N_NODES;
    int n = i - r * N_NODES;
    return (int)((degu[n] >> (16 * r)) & 0xFFFF);
}

// ---- 3-phase exclusive scan over concatenated masked degrees [4N] ----
__global__ __launch_bounds__(256) void scan_reduce_kernel(const unsigned long long* __restrict__ degu,
                                                          int* __restrict__ bsum) {
    __shared__ int sm[256];
    int b = blockIdx.x, t = threadIdx.x;
    int base = b * SCHUNK + t * 8;
    int s = 0;
#pragma unroll
    for (int i = 0; i < 8; ++i) {
        int idx = base + i;
        if (idx < M_SCAN) s += scan_val(degu, idx);
    }
    sm[t] = s;
    __syncthreads();
    for (int st = 128; st > 0; st >>= 1) {
        if (t < st) sm[t] += sm[t + st];
        __syncthreads();
    }
    if (t == 0) bsum[b] = sm[0];
}

__global__ __launch_bounds__(256) void scan_mid_kernel(const int* __restrict__ bsum,
                                                       int* __restrict__ boff,
                                                       int* __restrict__ rel_rp) {
    __shared__ int sm[256];
    int t = threadIdx.x;
    int v = (t < NSB) ? bsum[t] : 0;
    sm[t] = v;
    __syncthreads();
    for (int st = 1; st < 256; st <<= 1) {
        int u = (t >= st) ? sm[t - st] : 0;
        __syncthreads();
        sm[t] += u;
        __syncthreads();
    }
    if (t < NSB) boff[t] = sm[t] - v;
    if (t == NSB - 1) rel_rp[M_SCAN] = sm[t];
}

__global__ __launch_bounds__(256) void scan_final_kernel(const unsigned long long* __restrict__ degu,
                                                         const int* __restrict__ boff,
                                                         int* __restrict__ rel_rp) {
    __shared__ int sm[256];
    int b = blockIdx.x, t = threadIdx.x;
    int base = b * SCHUNK + t * 8;
    int v[8];
    int s = 0;
#pragma unroll
    for (int i = 0; i < 8; ++i) {
        int idx = base + i;
        v[i] = (idx < M_SCAN) ? scan_val(degu, idx) : 0;
        s += v[i];
    }
    sm[t] = s;
    __syncthreads();
    for (int st = 1; st < 256; st <<= 1) {
        int u = (t >= st) ? sm[t - st] : 0;
        __syncthreads();
        sm[t] += u;
        __syncthreads();
    }
    int run = sm[t] - s + boff[b];
#pragma unroll
    for (int i = 0; i < 8; ++i) {
        int idx = base + i;
        if (idx < M_SCAN) { rel_rp[idx] = run; run += v[i]; }
    }
}

// ---- radix-style CSR build ----
__global__ __launch_bounds__(256) void binA_kernel(const int* __restrict__ dst,
                                                   int* __restrict__ gcount) {
    __shared__ int h[NBUCK];
    for (int i = threadIdx.x; i < NBUCK; i += 256) h[i] = 0;
    __syncthreads();
    int e0 = blockIdx.x * ECHUNK;
    int e1 = min(e0 + ECHUNK, N_EDGES);
    for (int e = e0 + threadIdx.x; e < e1; e += 256)
        atomicAdd(&h[dst[e] >> 9], 1);
    __syncthreads();
    for (int i = threadIdx.x; i < NBUCK; i += 256)
        gcount[blockIdx.x * NBUCK + i] = h[i];
}

__global__ __launch_bounds__(256) void mscan_col_kernel(const int* __restrict__ gcount,
                                                        int* __restrict__ gbase,
                                                        int* __restrict__ btot) {
    __shared__ int sm[256];
    const int bk = blockIdx.x;
    const int t  = threadIdx.x;
    int v[PERT];
    int s = 0;
#pragma unroll
    for (int i = 0; i < PERT; ++i) {
        int blk = t * PERT + i;
        v[i] = gcount[blk * NBUCK + bk];
        s += v[i];
    }
    sm[t] = s;
    __syncthreads();
    for (int st = 1; st < 256; st <<= 1) {
        int u = (t >= st) ? sm[t - st] : 0;
        __syncthreads();
        sm[t] += u;
        __syncthreads();
    }
    int run = sm[t] - s;
#pragma unroll
    for (int i = 0; i < PERT; ++i) {
        int blk = t * PERT + i;
        gbase[blk * NBUCK + bk] = run;
        run += v[i];
    }
    if (t == 255) btot[bk] = run;
}

__global__ __launch_bounds__(256) void mscan_row_kernel(const int* __restrict__ btot,
                                                        int* __restrict__ bucketbase) {
    __shared__ int sm[256];
    int t = threadIdx.x;
    int v = (t < NBUCK) ? btot[t] : 0;
    sm[t] = v;
    __syncthreads();
    for (int st = 1; st < 256; st <<= 1) {
        int u = (t >= st) ? sm[t - st] : 0;
        __syncthreads();
        sm[t] += u;
        __syncthreads();
    }
    if (t < NBUCK) bucketbase[t] = sm[t] - v;
    if (t == NBUCK - 1) bucketbase[NBUCK] = sm[t];
}

// rec = src(17b) | dstlocal(9b)<<17 | maskbits(4b)<<26
__global__ __launch_bounds__(256) void binB_kernel(const int* __restrict__ src,
                                                   const int* __restrict__ dst,
                                                   const uint8_t* __restrict__ mask,
                                                   const int* __restrict__ flag,
                                                   const int* __restrict__ gbase,
                                                   const int* __restrict__ bucketbase,
                                                   unsigned int* __restrict__ recs) {
    __shared__ int cur[NBUCK];
    for (int i = threadIdx.x; i < NBUCK; i += 256) cur[i] = 0;
    __syncthreads();
    int bm = *flag;
    int e0 = blockIdx.x * ECHUNK;
    int e1 = min(e0 + ECHUNK, N_EDGES);
    for (int e = e0 + threadIdx.x; e < e1; e += 256) {
        int d = dst[e], s = src[e];
        int bits = 0;
        if (read_mask(mask, bm, (size_t)0 * N_EDGES + e)) bits |= 1;
        if (read_mask(mask, bm, (size_t)1 * N_EDGES + e)) bits |= 2;
        if (read_mask(mask, bm, (size_t)2 * N_EDGES + e)) bits |= 4;
        if (read_mask(mask, bm, (size_t)3 * N_EDGES + e)) bits |= 8;
        int bk  = d >> 9;
        int loc = atomicAdd(&cur[bk], 1);
        int pos = bucketbase[bk] + gbase[blockIdx.x * NBUCK + bk] + loc;
        recs[pos] = (unsigned)s | ((unsigned)(d & 511) << 17) | ((unsigned)bits << 26);
    }
}

// masked degrees from recs (LDS counters) -> degu packed + norm
__global__ __launch_bounds__(256) void count_norm_kernel(const unsigned int* __restrict__ recs,
                                                         const int* __restrict__ bucketbase,
                                                         unsigned long long* __restrict__ degu,
                                                         float* __restrict__ norm) {
    __shared__ int cnt[4 * BUCKSZ];
    const int t = threadIdx.x, b = blockIdx.x;
    const int lo = b * BUCKSZ;
    const int hi = min(lo + BUCKSZ, N_NODES);
    for (int i = t; i < 4 * BUCKSZ; i += 256) cnt[i] = 0;
    __syncthreads();

    const int e0 = bucketbase[b], e1 = bucketbase[b + 1];
    for (int i = e0 + t; i < e1; i += 256) {
        unsigned rec = recs[i];
        int dl   = (rec >> 17) & 0x1FF;
        int bits = (rec >> 26) & 0xF;
#pragma unroll
        for (int r = 0; r < 4; ++r)
            if ((bits >> r) & 1) atomicAdd(&cnt[r * BUCKSZ + dl], 1);
    }
    __syncthreads();

    for (int n = lo + t; n < hi; n += 256) {
        int dl = n - lo;
        unsigned long long u = 0;
#pragma unroll
        for (int r = 0; r < 4; ++r) {
            int c = cnt[r * BUCKSZ + dl];
            u |= ((unsigned long long)(c & 0xFFFF)) << (16 * r);
            norm[r * N_NODES + n] = 1.0f / sqrtf(fmaxf((float)c, 1.0f));
        }
        degu[n] = u;
    }
}

// one block per bucket: build per-(r,node) CSR in LDS, stream out.
__global__ __launch_bounds__(256) void csr_kernel(const unsigned int* __restrict__ recs,
                                                  const int* __restrict__ bucketbase,
                                                  const int* __restrict__ rel_rp,
                                                  int* __restrict__ rel_src) {
    __shared__ int cur[4 * BUCKSZ];
    __shared__ int lb[5];
    __shared__ int csr[P2CAP];
    const int t = threadIdx.x, b = blockIdx.x;
    const int lo = b * BUCKSZ;
    const int hi = min(lo + BUCKSZ, N_NODES);

    if (t == 0) {
        int run = 0;
#pragma unroll
        for (int r = 0; r < 4; ++r) {
            lb[r] = run;
            run += rel_rp[r * N_NODES + hi] - rel_rp[r * N_NODES + lo];
        }
        lb[4] = run;
    }
    __syncthreads();
    const int tot  = lb[4];
    const bool fits = (tot <= P2CAP);

#pragma unroll
    for (int r = 0; r < 4; ++r)
        for (int n = lo + t; n < hi; n += 256)
            cur[r * BUCKSZ + (n - lo)] = rel_rp[r * N_NODES + n] - rel_rp[r * N_NODES + lo];
    __syncthreads();

    const int e0 = bucketbase[b], e1 = bucketbase[b + 1];
    for (int i = e0 + t; i < e1; i += 256) {
        unsigned rec = recs[i];
        int s    = rec & 0x1FFFF;
        int dl   = (rec >> 17) & 0x1FF;
        int bits = (rec >> 26) & 0xF;
#pragma unroll
        for (int r = 0; r < 4; ++r) {
            if ((bits >> r) & 1) {
                int k = atomicAdd(&cur[r * BUCKSZ + dl], 1);
                if (fits) csr[lb[r] + k] = s;
                else      rel_src[rel_rp[r * N_NODES + lo] + k] = s;
            }
        }
    }
    __syncthreads();

    if (fits) {
        for (int j = t; j < tot; j += 256) {
            int r = (j >= lb[1]) + (j >= lb[2]) + (j >= lb[3]);
            rel_src[rel_rp[r * N_NODES + lo] + (j - lb[r])] = csr[j];
        }
    }
}

// pack W[r][384][64] fp32 -> Wpk frags [r][ks][nb][lane][8] bf16
__global__ __launch_bounds__(256) void pack_w_kernel(const float* __restrict__ W,
                                                     unsigned short* __restrict__ Wpk) {
    int t = blockIdx.x * blockDim.x + threadIdx.x;   // 12288
    if (t >= N_REL * 12 * 4 * 64) return;
    int lane = t & 63;
    int nb   = (t >> 6) & 3;
    int ks   = (t >> 8) % 12;
    int r    = t / 3072;
    const float* Wr = W + (size_t)r * 384 * 64;
    int k0 = ks * 32 + (lane >> 4) * 8;
    int n  = nb * 16 + (lane & 15);
    unsigned short* o = Wpk + (size_t)t * 8;
#pragma unroll
    for (int i = 0; i < 8; ++i)
        o[i] = f2b(Wr[(size_t)(k0 + i) * 64 + n]);
}

// x fp32 -> bf16
__global__ __launch_bounds__(256) void xb_kernel(const float* __restrict__ x,
                                                 unsigned short* __restrict__ xb) {
    int i = blockIdx.x * blockDim.x + threadIdx.x;
    if (i >= N_NODES * (D_IN / 4)) return;
    float4 v = ((const float4*)x)[i];
    ushort4 u;
    u.x = f2b(v.x); u.y = f2b(v.y); u.z = f2b(v.z); u.w = f2b(v.w);
    ((ushort4*)xb)[i] = u;
}

// ---- gather body (strides in elements) ----
template <int BF16IN>
__device__ inline void gather_body(const void* __restrict__ hin_, int in_stride,
                                   const int* __restrict__ rp,
                                   const int* __restrict__ rel_src,
                                   const float* __restrict__ normr,
                                   unsigned short* __restrict__ hout, int out_stride,
                                   int blk) {
    const int lane = threadIdx.x & 63;
    const int wave = (blk * 256 + (int)threadIdx.x) >> 6;
    const int g    = lane >> 4;
    const int l16  = lane & 15;
    const int node = wave * 4 + g;
    const int fb   = l16 * 8;

    const bool valid = (node < N_NODES);
    int e0 = valid ? rp[node] : 0;
    int e1 = valid ? rp[node + 1] : 0;

    float a[8];
#pragma unroll
    for (int j = 0; j < 8; ++j) a[j] = 0.0f;

    for (int base = e0; base < e1; base += 16) {
        int m = min(16, e1 - base);
        int   s_l = (l16 < m) ? rel_src[base + l16] : 0;
        float w_l = (l16 < m) ? normr[s_l] : 0.0f;

        for (int i = 0; i < m; i += 4) {
            int   i1 = min(i + 1, m - 1), i2 = min(i + 2, m - 1), i3 = min(i + 3, m - 1);
            int   s0 = __shfl(s_l, i,  16);
            int   s1 = __shfl(s_l, i1, 16);
            int   s2 = __shfl(s_l, i2, 16);
            int   s3 = __shfl(s_l, i3, 16);
            float w0 = __shfl(w_l, i,  16);
            float w1 = (i + 1 < m) ? __shfl(w_l, i1, 16) : 0.0f;
            float w2 = (i + 2 < m) ? __shfl(w_l, i2, 16) : 0.0f;
            float w3 = (i + 3 < m) ? __shfl(w_l, i3, 16) : 0.0f;

            if (BF16IN) {
                const unsigned short* hp = (const unsigned short*)hin_;
                s16x8 v0 = *(const s16x8*)(hp + (size_t)s0 * in_stride + fb);
                s16x8 v1 = *(const s16x8*)(hp + (size_t)s1 * in_stride + fb);
                s16x8 v2 = *(const s16x8*)(hp + (size_t)s2 * in_stride + fb);
                s16x8 v3 = *(const s16x8*)(hp + (size_t)s3 * in_stride + fb);
#pragma unroll
                for (int j = 0; j < 8; ++j) {
                    a[j] += w0 * b2f((unsigned short)v0[j]);
                    a[j] += w1 * b2f((unsigned short)v1[j]);
                    a[j] += w2 * b2f((unsigned short)v2[j]);
                    a[j] += w3 * b2f((unsigned short)v3[j]);
                }
            } else {
                const float* xp = (const float*)hin_;
                float4 u0  = *(const float4*)(xp + (size_t)s0 * in_stride + fb);
                float4 u0b = *(const float4*)(xp + (size_t)s0 * in_stride + fb + 4);
                float4 u1  = *(const float4*)(xp + (size_t)s1 * in_stride + fb);
                float4 u1b = *(const float4*)(xp + (size_t)s1 * in_stride + fb + 4);
                float4 u2  = *(const float4*)(xp + (size_t)s2 * in_stride + fb);
                float4 u2b = *(const float4*)(xp + (size_t)s2 * in_stride + fb + 4);
                float4 u3  = *(const float4*)(xp + (size_t)s3 * in_stride + fb);
                float4 u3b = *(const float4*)(xp + (size_t)s3 * in_stride + fb + 4);
                a[0] += w0 * u0.x + w1 * u1.x + w2 * u2.x + w3 * u3.x;
                a[1] += w0 * u0.y + w1 * u1.y + w2 * u2.y + w3 * u3.y;
                a[2] += w0 * u0.z + w1 * u1.z + w2 * u2.z + w3 * u3.z;
                a[3] += w0 * u0.w + w1 * u1.w + w2 * u2.w + w3 * u3.w;
                a[4] += w0 * u0b.x + w1 * u1b.x + w2 * u2b.x + w3 * u3b.x;
                a[5] += w0 * u0b.y + w1 * u1b.y + w2 * u2b.y + w3 * u3b.y;
                a[6] += w0 * u0b.z + w1 * u1b.z + w2 * u2b.z + w3 * u3b.z;
                a[7] += w0 * u0b.w + w1 * u1b.w + w2 * u2b.w + w3 * u3b.w;
            }
        }
    }

    if (valid) {
        float c = normr[node];
        s16x8 r;
#pragma unroll
        for (int j = 0; j < 8; ++j) r[j] = (short)f2b(a[j] * c);
        *(s16x8*)(hout + (size_t)node * out_stride + fb) = r;
    }
}

template <int BF16IN>
__global__ __launch_bounds__(256) void gather_kernel(const void* __restrict__ hin_, int in_stride,
                                                     const int* __restrict__ rp,
                                                     const int* __restrict__ rel_src,
                                                     const float* __restrict__ normr,
                                                     unsigned short* __restrict__ hout, int out_stride) {
    gather_body<BF16IN>(hin_, in_stride, rp, rel_src, normr, hout, out_stride, blockIdx.x);
}

// ---- gemm body: h1 from the STASH inside out; sync before epilogue overwrite ----
template <int XB16>
__device__ inline void gemm_body(const void* __restrict__ x_,
                                 const unsigned short* __restrict__ h1s,
                                 const unsigned short* __restrict__ h2b,
                                 const unsigned short* __restrict__ Wpk,
                                 const float* __restrict__ bias,
                                 float* __restrict__ out,
                                 int blk) {
    const int wave = threadIdx.x >> 6;
    const int lane = threadIdx.x & 63;
    const int rb   = blk * 64 + wave * 16;
    const int row  = min(rb + (lane & 15), N_NODES - 1);
    const int kq   = (lane >> 4) * 8;

    f32x4 acc0 = {0.f, 0.f, 0.f, 0.f};
    f32x4 acc1 = {0.f, 0.f, 0.f, 0.f};
    f32x4 acc2 = {0.f, 0.f, 0.f, 0.f};
    f32x4 acc3 = {0.f, 0.f, 0.f, 0.f};

    const s16x8* Wf = (const s16x8*)Wpk;

#pragma unroll
    for (int ks = 0; ks < 12; ++ks) {
        s16x8 a;
        const int koff = (ks & 3) * 32 + kq;
        if (ks < 4) {
            if (XB16) {
                a = *(const s16x8*)((const unsigned short*)x_ + (size_t)row * D_IN + koff);
            } else {
                const float* p = (const float*)x_ + (size_t)row * D_IN + koff;
                float4 f0 = *(const float4*)p;
                float4 f1 = *(const float4*)(p + 4);
                a[0] = (short)f2b(f0.x); a[1] = (short)f2b(f0.y);
                a[2] = (short)f2b(f0.z); a[3] = (short)f2b(f0.w);
                a[4] = (short)f2b(f1.x); a[5] = (short)f2b(f1.y);
                a[6] = (short)f2b(f1.z); a[7] = (short)f2b(f1.w);
            }
        } else if (ks < 8) {
            a = *(const s16x8*)(h1s + (size_t)row * STASH_STRIDE + koff);
        } else {
            a = *(const s16x8*)(h2b + (size_t)row * D_IN + koff);
        }
        const s16x8* bks = Wf + ks * 256 + lane;
        acc0 = __builtin_amdgcn_mfma_f32_16x16x32_bf16(a, bks[0],   acc0, 0, 0, 0);
        acc1 = __builtin_amdgcn_mfma_f32_16x16x32_bf16(a, bks[64],  acc1, 0, 0, 0);
        acc2 = __builtin_amdgcn_mfma_f32_16x16x32_bf16(a, bks[128], acc2, 0, 0, 0);
        acc3 = __builtin_amdgcn_mfma_f32_16x16x32_bf16(a, bks[192], acc3, 0, 0, 0);
    }

    __syncthreads();   // all stash reads done before epilogue overwrites stash

    const int orow0 = rb + (lane >> 4) * 4;
    const int jc    = lane & 15;
    f32x4 accs[4] = {acc0, acc1, acc2, acc3};
#pragma unroll
    for (int nb = 0; nb < 4; ++nb) {
        float bz = bias[nb * 16 + jc];
#pragma unroll
        for (int i = 0; i < 4; ++i) {
            int n = orow0 + i;
            if (n < N_NODES)
                out[(size_t)n * OUT_STRIDE + nb * 16 + jc] = fmaxf(accs[nb][i] + bz, 0.0f);
        }
    }
}

template <int XB16>
__global__ __launch_bounds__(256) void gemm_kernel(const void* __restrict__ x_,
                                                   const unsigned short* __restrict__ h1s,
                                                   const unsigned short* __restrict__ h2b,
                                                   const unsigned short* __restrict__ Wpk,
                                                   const float* __restrict__ bias,
                                                   float* __restrict__ out) {
    gemm_body<XB16>(x_, h1s, h2b, Wpk, bias, out, blockIdx.x);
}

// shallow fused: gemm(r) + hop1(r+1)
template <int XB16>
__global__ __launch_bounds__(256) void fused_kernel(const void* __restrict__ x_,
                                                    const unsigned short* __restrict__ h1s,
                                                    const unsigned short* __restrict__ h2b,
                                                    const unsigned short* __restrict__ Wpk,
                                                    const float* __restrict__ bias,
                                                    float* __restrict__ out,
                                                    const int* __restrict__ rp_n,
                                                    const int* __restrict__ rel_src,
                                                    const float* __restrict__ norm_n,
                                                    unsigned short* __restrict__ stash_n) {
    if (blockIdx.x < GEMMG) {
        gemm_body<XB16>(x_, h1s, h2b, Wpk, bias, out, blockIdx.x);
    } else {
        gather_body<XB16>(x_, D_IN, rp_n, rel_src, norm_n, stash_n, STASH_STRIDE,
                          blockIdx.x - GEMMG);
    }
}

// deep prologue fused2: hop2(0): stash0 -> h2cur  ||  hop1(1): x -> stash1
template <int XB16>
__global__ __launch_bounds__(256) void fused2_kernel(const void* __restrict__ x_,
                                                     const int* __restrict__ rel_src,
                                                     const unsigned short* __restrict__ stash0,
                                                     const int* __restrict__ rp0,
                                                     const float* __restrict__ norm0,
                                                     unsigned short* __restrict__ h2cur,
                                                     const int* __restrict__ rp1,
                                                     const float* __restrict__ norm1,
                                                     unsigned short* __restrict__ stash1) {
    if (blockIdx.x < GATHG) {
        gather_body<1>(stash0, STASH_STRIDE, rp0, rel_src, norm0, h2cur, D_IN, blockIdx.x);
    } else {
        gather_body<XB16>(x_, D_IN, rp1, rel_src, norm1, stash1, STASH_STRIDE,
                          blockIdx.x - GATHG);
    }
}

// deep fused3: gemm(r)[stash_r,h2cur] || hop2(r+1): stash_r1 -> h2next
//              || (optional) hop1(r+2): x -> stash_r2
template <int XB16>
__global__ __launch_bounds__(256) void fused3_kernel(const void* __restrict__ x_,
                                                     const int* __restrict__ rel_src,
                                                     const unsigned short* __restrict__ stash_r,
                                                     const unsigned short* __restrict__ h2cur,
                                                     const unsigned short* __restrict__ Wpk,
                                                     const float* __restrict__ bias,
                                                     float* __restrict__ out,
                                                     const int* __restrict__ rp1,
                                                     const float* __restrict__ norm1,
                                                     const unsigned short* __restrict__ stash_r1,
                                                     unsigned short* __restrict__ h2next,
                                                     const int* __restrict__ rp2,
                                                     const float* __restrict__ norm2,
                                                     unsigned short* __restrict__ stash_r2) {
    if (blockIdx.x < GEMMG) {
        gemm_body<XB16>(x_, stash_r, h2cur, Wpk, bias, out, blockIdx.x);
    } else if (blockIdx.x < GEMMG + GATHG) {
        gather_body<1>(stash_r1, STASH_STRIDE, rp1, rel_src, norm1, h2next, D_IN,
                       blockIdx.x - GEMMG);
    } else {
        gather_body<XB16>(x_, D_IN, rp2, rel_src, norm2, stash_r2, STASH_STRIDE,
                          blockIdx.x - GEMMG - GATHG);
    }
}

extern "C" void kernel_launch(void* const* d_in, const int* in_sizes, int n_in,
                              void* d_out, int out_size, void* d_ws, size_t ws_size,
                              hipStream_t stream) {
    const float*   x    = (const float*)d_in[0];
    const int*     src  = (const int*)d_in[1];
    const int*     dst  = (const int*)d_in[2];
    const uint8_t* mask = (const uint8_t*)d_in[3];
    const float*   W    = (const float*)d_in[4];     // [4][384][64]
    const float*   b    = (const float*)d_in[5];     // [4][64]
    float*         out  = (float*)d_out;             // [N][256]

    int*                flag    = (int*)d_ws;
    unsigned long long* degu    = (unsigned long long*)((char*)d_ws + 256);
    float*              norm    = (float*)(degu + N_NODES);
    int*                rel_rp  = (int*)(norm + (size_t)N_REL * N_NODES);
    int*                bsum    = rel_rp + M_SCAN + 16;
    int*                boff    = bsum + 256;
    int*                gcount  = boff + 256;
    int*                gbase   = gcount + FILLB * NBUCK;
    int*                bktbase = gbase + FILLB * NBUCK;
    int*                btot    = bktbase + 256;
    unsigned int*       recs    = (unsigned int*)(btot + 256);
    int*                rel_src = (int*)(recs + N_EDGES);
    unsigned short*     Wpk     = (unsigned short*)(rel_src + REL_CAP);
    unsigned short*     h2_0    = Wpk + 12288 * 8;
    unsigned short*     h2_1    = h2_0 + NH;          // deep only
    unsigned short*     xb_deep = h2_1 + NH;
    unsigned short*     xb_shal = h2_0 + NH;          // shallow xb aliases h2_1

    const size_t need_deep = (size_t)((char*)(xb_deep + NH) - (char*)d_ws);
    const size_t need_shal = (size_t)((char*)(xb_shal + NH) - (char*)d_ws);
    const int deep   = (ws_size >= need_deep);
    const int use_xb = deep || (ws_size >= need_shal);
    unsigned short* xb = deep ? xb_deep : xb_shal;

    hipMemsetAsync(d_ws, 0, 256, stream);

    detect_mask_kernel<<<64, 256, 0, stream>>>(mask, flag);

    binA_kernel<<<FILLB, 256, 0, stream>>>(dst, gcount);
    mscan_col_kernel<<<NBUCK, 256, 0, stream>>>(gcount, gbase, btot);
    mscan_row_kernel<<<1, 256, 0, stream>>>(btot, bktbase);
    binB_kernel<<<FILLB, 256, 0, stream>>>(src, dst, mask, flag, gbase, bktbase, recs);

    count_norm_kernel<<<NBUCK, 256, 0, stream>>>(recs, bktbase, degu, norm);

    scan_reduce_kernel<<<NSB, 256, 0, stream>>>(degu, bsum);
    scan_mid_kernel<<<1, 256, 0, stream>>>(bsum, boff, rel_rp);
    scan_final_kernel<<<NSB, 256, 0, stream>>>(degu, boff, rel_rp);

    csr_kernel<<<NBUCK, 256, 0, stream>>>(recs, bktbase, rel_rp, rel_src);

    pack_w_kernel<<<48, 256, 0, stream>>>(W, Wpk);
    if (use_xb)
        xb_kernel<<<(N_NODES * (D_IN / 4) + 255) / 256, 256, 0, stream>>>(x, xb);

    const void* xin = use_xb ? (const void*)xb : (const void*)x;

    unsigned short* stash[N_REL];
    for (int r = 0; r < N_REL; ++r)
        stash[r] = (unsigned short*)out + (size_t)r * 128;

    if (deep) {
        // deep pipeline: h2 double-buffered; all gathers after prologue hidden
        gather_kernel<1><<<GATHG, 256, 0, stream>>>(xin, D_IN, rel_rp, rel_src,
                                                    norm, stash[0], STASH_STRIDE);
        fused2_kernel<1><<<2 * GATHG, 256, 0, stream>>>(
            xin, rel_src, stash[0], rel_rp, norm, h2_0,
            rel_rp + (size_t)N_NODES, norm + (size_t)N_NODES, stash[1]);

        unsigned short* h2buf[2] = {h2_0, h2_1};
        for (int r = 0; r < N_REL; ++r) {
            const unsigned short* Wr = Wpk + (size_t)r * 3072 * 8;
            const float* br = b + (size_t)r * D_OUT;
            float* outr = out + (size_t)r * D_OUT;
            if (r < N_REL - 1) {
                const int*   rp1 = rel_rp + (size_t)(r + 1) * N_NODES;
                const float* n1  = norm + (size_t)(r + 1) * N_NODES;
                const bool hop1 = (r + 2 < N_REL);
                const int*   rp2 = hop1 ? rel_rp + (size_t)(r + 2) * N_NODES : rel_rp;
                const float* n2  = hop1 ? norm + (size_t)(r + 2) * N_NODES : norm;
                unsigned short* st2 = hop1 ? stash[r + 2] : stash[0];
                int grid = GEMMG + GATHG + (hop1 ? GATHG : 0);
                fused3_kernel<1><<<grid, 256, 0, stream>>>(
                    xin, rel_src, stash[r], h2buf[r & 1], Wr, br, outr,
                    rp1, n1, stash[r + 1], h2buf[(r + 1) & 1],
                    rp2, n2, st2);
            } else {
                gemm_kernel<1><<<GEMMG, 256, 0, stream>>>(xin, stash[r], h2buf[r & 1],
                                                          Wr, br, outr);
            }
        }
    } else {
        // shallow fallback: single h2
        if (use_xb)
            gather_kernel<1><<<GATHG, 256, 0, stream>>>(xin, D_IN, rel_rp, rel_src,
                                                        norm, stash[0], STASH_STRIDE);
        else
            gather_kernel<0><<<GATHG, 256, 0, stream>>>(xin, D_IN, rel_rp, rel_src,
                                                        norm, stash[0], STASH_STRIDE);
        gather_kernel<1><<<GATHG, 256, 0, stream>>>(stash[0], STASH_STRIDE, rel_rp, rel_src,
                                                    norm, h2_0, D_IN);

        for (int r = 0; r < N_REL; ++r) {
            const unsigned short* Wr = Wpk + (size_t)r * 3072 * 8;
            const float* br = b + (size_t)r * D_OUT;
            float* outr = out + (size_t)r * D_OUT;
            if (r < N_REL - 1) {
                const float* n1  = norm + (size_t)(r + 1) * N_NODES;
                const int*   rp1 = rel_rp + (size_t)(r + 1) * N_NODES;
                if (use_xb)
                    fused_kernel<1><<<GEMMG + GATHG, 256, 0, stream>>>(
                        xin, stash[r], h2_0, Wr, br, outr, rp1, rel_src, n1, stash[r + 1]);
                else
                    fused_kernel<0><<<GEMMG + GATHG, 256, 0, stream>>>(
                        xin, stash[r], h2_0, Wr, br, outr, rp1, rel_src, n1, stash[r + 1]);
                gather_kernel<1><<<GATHG, 256, 0, stream>>>(stash[r + 1], STASH_STRIDE,
                                                            rp1, rel_src, n1, h2_0, D_IN);
            } else {
                if (use_xb)
                    gemm_kernel<1><<<GEMMG, 256, 0, stream>>>(xin, stash[r], h2_0, Wr, br, outr);
                else
                    gemm_kernel<0><<<GEMMG, 256, 0, stream>>>(xin, stash[r], h2_0, Wr, br, outr);
            }
        }
    }
}